// Round 2
// baseline (3366.132 us; speedup 1.0000x reference)
//
#include <hip/hip_runtime.h>

#define B_ 256
#define T_ 500
#define I_ 8
#define H_ 1024
#define O_ 8
#define NSTEP (T_ - 1)
#define EXC_N 819   // int(0.8 * 1024)

typedef unsigned short u16;
typedef __attribute__((ext_vector_type(8))) short short8;
typedef __attribute__((ext_vector_type(4))) float f32x4;

// r-exchange ping-pong + per-group flag line in module globals.
__device__ __attribute__((aligned(16))) u16 g_rbuf[2 * B_ * H_];
// 16 groups x 16 producer flags, each group's flags in ONE 64B line,
// groups padded to 128B so they don't interfere.
__device__ __attribute__((aligned(128))) unsigned int g_flag[16 * 32];

__device__ __forceinline__ float bf2f(u16 u) {
    union { unsigned int i; float f; } v;
    v.i = ((unsigned int)u) << 16;
    return v.f;
}
__device__ __forceinline__ u16 f2bf(float f) {
    union { float f; unsigned int i; } v;
    v.f = f;
    unsigned int u = v.i;
    return (u16)((u + 0x7fffu + ((u >> 16) & 1u)) >> 16);
}
__device__ __forceinline__ float sp_(float v) {   // softplus, beta=1
    float e = __expf(-fabsf(v));
    return fmaxf(v, 0.0f) + __logf(1.0f + e);
}

__global__ void rnn_init() {
    g_flag[threadIdx.x] = 0u;
    g_flag[threadIdx.x + 256] = 0u;
}

// SYNC SCHEME (this revision):
//  release: r sc1-stores -> s_waitcnt vmcnt(0) -> __syncthreads ->
//           per-producer FLAG store (plain relaxed agent store, one-way,
//           NO RMW -> no 16-way serialization at the coherence point).
//  acquire: every wave polls the group's 16-flag line itself (one coalesced
//           64B load + __ballot per iteration). A wave exits when ITS 4
//           producers (wave w consumes k in [256w,256w+256) = producers
//           4w..4w+3) are ready, then immediately issues its A-frag loads.
//           No post-poll __syncthreads.
//  write guard (ping-pong reuse): overwriting buf[(t+1)&1] at step t needs
//           all 16 flags >= t (flag v => that WG's A-load of buf[(v-1)&1]
//           drained). Usually witnessed for free by the SAME ballot at the
//           previous poll (all16_ok); only if not, a short poll runs before
//           the r-store.
//  ordering hygiene: out-store + noise/x prefetches are issued AFTER the
//           poll (vmcnt is in-order; anything issued before the poll load
//           inflates every poll iteration's waitcnt).
__global__ void __launch_bounds__(256, 1)
rnn_persist(const float* __restrict__ x, const float* __restrict__ noise,
            const float* __restrict__ wi, const float* __restrict__ wrec,
            const float* __restrict__ wout, const float* __restrict__ bb,
            const float* __restrict__ gg, const float* __restrict__ h0,
            const float* __restrict__ mwrec, float* __restrict__ out)
{
    const int bid = blockIdx.x;
    const int grp = bid & 15;        // batch group (16 rows)
    const int ntw = bid >> 4;        // j-slice 0..15 (also producer id)
    const int jb  = ntw * 64;
    const int tid = threadIdx.x;
    const int w   = tid >> 6;        // wave = K-slice of 256
    const int l   = tid & 63;
    const int lm  = l & 15;
    const int lk  = l >> 4;
    const int kb  = w * 256;
    const int je  = jb + l;          // epilogue thread's j

    __shared__ float part[4 * 16 * 68];   // [wave][m][jj pad 68] fp32 partials
    __shared__ float xbuf[16 * 8];
    __shared__ float outred[64];

    // ---- per-thread constants ----
    float wiv[8];
#pragma unroll
    for (int i = 0; i < 8; ++i) wiv[i] = wi[i * H_ + je];
    const float bTe = bb[je];
    float h[4];
    {
        float h0j = h0[je];
        h[0] = h[1] = h[2] = h[3] = h0j;
    }

    // ---- B fragments: effWg[k][j] = relu(wrec[j,k]*ei[k])*ei[k]*mwrec[j,k]*relu(g[k]) ----
    // B layout (16x16x32): col = lane&15, k = kf*32 + 8*(lane>>4) + i
    short8 Bf[8][4];
#pragma unroll
    for (int kf = 0; kf < 8; ++kf) {
#pragma unroll
        for (int n4 = 0; n4 < 4; ++n4) {
            const int jB = jb + n4 * 16 + lm;
            const int k0 = kb + kf * 32 + 8 * lk;
            short8 r;
#pragma unroll
            for (int i = 0; i < 8; ++i) {
                const int k = k0 + i;
                const float ei = (k < EXC_N) ? 1.0f : -1.0f;
                const float wf = wrec[jB * H_ + k];
                const float mf = mwrec[jB * H_ + k];
                const float gf = fmaxf(gg[k], 0.0f);
                const float e  = fmaxf(wf * ei, 0.0f) * ei * mf * gf;
                r[i] = (short)f2bf(e);
            }
            Bf[kf][n4] = r;
        }
    }

    // ---- wout column slice (only WGs ntw<8 produce output column ntw) ----
    float wo[64];
    if (ntw < O_) {
#pragma unroll
        for (int kf = 0; kf < 8; ++kf)
#pragma unroll
            for (int i = 0; i < 8; ++i) {
                const int k = kb + kf * 32 + 8 * lk + i;
                wo[kf * 8 + i] = wout[k * O_ + ntw];
            }
    }

    // ---- A fragments for t=0: r0[k] = softplus(h0[k]+b[k]), same for all rows ----
    short8 Af[8];
#pragma unroll
    for (int kf = 0; kf < 8; ++kf) {
        const int k0 = kb + kf * 32 + 8 * lk;
        short8 a;
#pragma unroll
        for (int i = 0; i < 8; ++i)
            a[i] = (short)f2bf(sp_(h0[k0 + i] + bb[k0 + i]));
        Af[kf] = a;
    }

    // ---- prefetch noise(0), x(0) ----
    float nprev[4];
#pragma unroll
    for (int q = 0; q < 4; ++q)
        nprev[q] = noise[(grp * 16 + w * 4 + q) * (T_ * H_) + je];
    float xp = 0.0f;
    if (tid < 128) xp = x[(grp * 16 + (tid >> 3)) * (T_ * I_) + (tid & 7)];

    unsigned int* flg = g_flag + grp * 32;   // this group's 16-flag line
    bool all16_ok = true;                     // flags>=0 trivially true at t=0

    for (int t = 0; t < NSTEP; ++t) {
        // stage x_t
        if (tid < 128) xbuf[tid] = xp;

        // MFMA: partial D = r_t @ effWg^T over this wave's K slice
        f32x4 acc0 = {0,0,0,0}, acc1 = {0,0,0,0}, acc2 = {0,0,0,0}, acc3 = {0,0,0,0};
#pragma unroll
        for (int kf = 0; kf < 8; ++kf) {
            acc0 = __builtin_amdgcn_mfma_f32_16x16x32_bf16(Af[kf], Bf[kf][0], acc0, 0, 0, 0);
            acc1 = __builtin_amdgcn_mfma_f32_16x16x32_bf16(Af[kf], Bf[kf][1], acc1, 0, 0, 0);
            acc2 = __builtin_amdgcn_mfma_f32_16x16x32_bf16(Af[kf], Bf[kf][2], acc2, 0, 0, 0);
            acc3 = __builtin_amdgcn_mfma_f32_16x16x32_bf16(Af[kf], Bf[kf][3], acc3, 0, 0, 0);
        }
        // D layout: m = 4*lk + reg, jj = n4*16 + lm
#pragma unroll
        for (int reg = 0; reg < 4; ++reg) {
            const int m = 4 * lk + reg;
            part[(w * 16 + m) * 68 +  0 + lm] = acc0[reg];
            part[(w * 16 + m) * 68 + 16 + lm] = acc1[reg];
            part[(w * 16 + m) * 68 + 32 + lm] = acc2[reg];
            part[(w * 16 + m) * 68 + 48 + lm] = acc3[reg];
        }
        __syncthreads();   // (a)

        // h update (fp32 state in regs), produce r_{t+1} (bf16)
        u16 rsto[4];
#pragma unroll
        for (int q = 0; q < 4; ++q) {
            const int m = w * 4 + q;
            float D = part[(0 * 16 + m) * 68 + l] + part[(1 * 16 + m) * 68 + l]
                    + part[(2 * 16 + m) * 68 + l] + part[(3 * 16 + m) * 68 + l];
            float inp = 0.0f;
#pragma unroll
            for (int i = 0; i < 8; ++i) inp = fmaf(xbuf[m * 8 + i], wiv[i], inp);
            float hn = h[q] + 0.05f * nprev[q] + 0.2f * (-h[q] + D + inp);
            hn = fminf(fmaxf(hn, -64.0f), 64.0f);   // inert if dynamics correct (|h|<~20)
            h[q] = hn;
            rsto[q] = f2bf(sp_(hn + bTe));
        }

        // write guard: overwriting buf[(t+1)&1] needs all 16 flags >= t.
        // Usually already witnessed by the previous poll's ballot.
        if (!all16_ok) {
            unsigned int f;
            do {
                f = __hip_atomic_load(flg + lm, __ATOMIC_RELAXED, __HIP_MEMORY_SCOPE_AGENT);
            } while (!__all((int)(f >= (unsigned int)t)));
        }
        asm volatile("" ::: "memory");

        // r store: pair-pack adjacent lanes' bf16 into u32, coherent store
        {
            unsigned int* rb32 = (unsigned int*)(g_rbuf + ((t + 1) & 1) * (B_ * H_)
                                                 + (grp * 16) * H_);
#pragma unroll
            for (int q = 0; q < 4; ++q) {
                unsigned int mine = (unsigned int)rsto[q];
                unsigned int nb   = (unsigned int)__shfl_xor((int)mine, 1, 64);
                if ((l & 1) == 0) {
                    unsigned int packed = (mine & 0xffffu) | (nb << 16);
                    __hip_atomic_store(rb32 + (((w * 4 + q) * H_ + je) >> 1), packed,
                                       __ATOMIC_RELAXED, __HIP_MEMORY_SCOPE_AGENT);
                }
            }
        }

        // output row t from r_t (Af): VALU compute BEFORE the drain so the
        // r-store acks arrive underneath it; the global store is deferred to
        // after the poll (keeps it out of every poll iteration's waitcnt).
        float outval = 0.0f;
        if (ntw < O_) {
            float po = 0.0f;
#pragma unroll
            for (int kf = 0; kf < 8; ++kf) {
                const short8 a = Af[kf];
#pragma unroll
                for (int i = 0; i < 8; ++i)
                    po = fmaf(bf2f((u16)a[i]), wo[kf * 8 + i], po);
            }
            po += __shfl_xor(po, 16, 64);
            po += __shfl_xor(po, 32, 64);
            if (l < 16) outred[w * 16 + l] = po;
            __syncthreads();   // (c)
            if (tid < 16)
                outval = outred[tid] + outred[16 + tid] + outred[32 + tid] + outred[48 + tid];
        }

        // release edge: drain this wave's coherent stores, barrier across the
        // 4 waves, then one-way flag store. NO RMW, NO cache maintenance.
        asm volatile("s_waitcnt vmcnt(0)" ::: "memory");
        __syncthreads();   // (b)
        if (tid == 0)
            __hip_atomic_store(flg + ntw, (unsigned int)(t + 1),
                               __ATOMIC_RELAXED, __HIP_MEMORY_SCOPE_AGENT);

        // acquire edge: all waves poll the 16-flag line (single coalesced
        // request/iter). Exit when THIS wave's 4 producers are ready; capture
        // whether all 16 were already ready (write guard for next step).
        unsigned long long rdy;
        {
            const unsigned int tgt = (unsigned int)(t + 1);
            do {
                unsigned int f = __hip_atomic_load(flg + lm, __ATOMIC_RELAXED,
                                                   __HIP_MEMORY_SCOPE_AGENT);
                rdy = __ballot((int)(f >= tgt));
            } while (((rdy >> (4 * w)) & 0xFull) != 0xFull);
        }
        all16_ok = (~rdy == 0ull);

        // A-frag loads for r_{t+1} (coherent u64 atomic loads, compiler-tracked)
        {
            u16* rbl = g_rbuf + ((t + 1) & 1) * (B_ * H_) + (grp * 16 + lm) * H_ + kb;
#pragma unroll
            for (int kf = 0; kf < 8; ++kf) {
                unsigned long long* p = (unsigned long long*)(rbl + kf * 32 + 8 * lk);
                unsigned long long d0 = __hip_atomic_load(p + 0, __ATOMIC_RELAXED,
                                                          __HIP_MEMORY_SCOPE_AGENT);
                unsigned long long d1 = __hip_atomic_load(p + 1, __ATOMIC_RELAXED,
                                                          __HIP_MEMORY_SCOPE_AGENT);
                union { unsigned long long q[2]; short8 s; } cv;
                cv.q[0] = d0; cv.q[1] = d1;
                Af[kf] = cv.s;
            }
        }

        // deferred out store + next-step stream prefetch (fire & forget;
        // overlap with next iteration's MFMA / LDS reduce)
        if (ntw < O_ && tid < 16)
            out[(grp * 16 + tid) * (T_ * O_) + t * O_ + ntw] = outval;
#pragma unroll
        for (int q = 0; q < 4; ++q)
            nprev[q] = noise[(grp * 16 + w * 4 + q) * (T_ * H_) + (t + 1) * H_ + je];
        if (tid < 128 && t + 1 < NSTEP)
            xp = x[(grp * 16 + (tid >> 3)) * (T_ * I_) + (t + 1) * I_ + (tid & 7)];
    }

    // output row T-1 from r_{T-1}
    if (ntw < O_) {
        float po = 0.0f;
#pragma unroll
        for (int kf = 0; kf < 8; ++kf) {
            const short8 a = Af[kf];
#pragma unroll
            for (int i = 0; i < 8; ++i)
                po = fmaf(bf2f((u16)a[i]), wo[kf * 8 + i], po);
        }
        po += __shfl_xor(po, 16, 64);
        po += __shfl_xor(po, 32, 64);
        if (l < 16) outred[w * 16 + l] = po;
        __syncthreads();
        if (tid < 16) {
            float s = outred[tid] + outred[16 + tid] + outred[32 + tid] + outred[48 + tid];
            out[(grp * 16 + tid) * (T_ * O_) + (T_ - 1) * O_ + ntw] = s;
        }
    }
}

extern "C" void kernel_launch(void* const* d_in, const int* in_sizes, int n_in,
                              void* d_out, int out_size, void* d_ws, size_t ws_size,
                              hipStream_t stream) {
    (void)in_sizes; (void)n_in; (void)out_size; (void)d_ws; (void)ws_size;
    const float* x     = (const float*)d_in[0];
    const float* noise = (const float*)d_in[1];
    const float* wi    = (const float*)d_in[2];
    const float* wrec  = (const float*)d_in[3];
    const float* wout  = (const float*)d_in[4];
    const float* bb    = (const float*)d_in[5];
    const float* gg    = (const float*)d_in[6];
    const float* h0    = (const float*)d_in[7];
    // d_in[8] = refEI: derived analytically (ei[k] = k<819 ? 1 : -1), not needed
    const float* mwrec = (const float*)d_in[9];
    float* out = (float*)d_out;

    rnn_init<<<dim3(1), dim3(256), 0, stream>>>();
    rnn_persist<<<dim3(256), dim3(256), 0, stream>>>(
        x, noise, wi, wrec, wout, bb, gg, h0, mwrec, out);
}

// Round 3
// 3083.950 us; speedup vs baseline: 1.0915x; 1.0915x over previous
//
#include <hip/hip_runtime.h>

#define B_ 256
#define T_ 500
#define I_ 8
#define H_ 1024
#define O_ 8
#define NSTEP (T_ - 1)
#define EXC_N 819   // int(0.8 * 1024)

typedef unsigned short u16;
typedef __attribute__((ext_vector_type(8))) short short8;
typedef __attribute__((ext_vector_type(4))) float f32x4;

// r-exchange ping-pong + per-group flag line in module globals.
__device__ __attribute__((aligned(16))) u16 g_rbuf[2 * B_ * H_];
// 16 groups x 16 producer flags; each group's 16 flags in ONE 64B line,
// groups padded to 128B so lines don't interfere.
__device__ __attribute__((aligned(128))) unsigned int g_flag[16 * 32];

__device__ __forceinline__ float bf2f(u16 u) {
    union { unsigned int i; float f; } v;
    v.i = ((unsigned int)u) << 16;
    return v.f;
}
__device__ __forceinline__ u16 f2bf(float f) {
    union { float f; unsigned int i; } v;
    v.f = f;
    unsigned int u = v.i;
    return (u16)((u + 0x7fffu + ((u >> 16) & 1u)) >> 16);
}
__device__ __forceinline__ float sp_(float v) {   // softplus, beta=1
    float e = __expf(-fabsf(v));
    return fmaxf(v, 0.0f) + __logf(1.0f + e);
}

__global__ void rnn_init() {
    g_flag[threadIdx.x] = 0u;
    g_flag[threadIdx.x + 256] = 0u;
}

// SYNC SCHEME (R3 = R1 structure, RMW-free, clean poll path):
//  release: r sc1-stores -> epilogue VALU (overlaps store acks) ->
//           s_waitcnt vmcnt(0) -> __syncthreads -> tid0 stores per-producer
//           FLAG = t+1 (plain relaxed agent store; no RMW, no serialization,
//           no cache maintenance).
//  acquire: wave 0 polls the group's 16-flag line (64 lanes load flg[l&15],
//           ONE coalesced 64B request/iter) until ALL 16 flags >= t+1, then
//           __syncthreads broadcasts. Waiting for all 16 (not just this
//           wave's producers) makes the ping-pong write guard free: at step
//           t we observed all flags >= t+1 => every WG finished step t's
//           r-stores => every WG consumed its step t-1 A-loads of
//           buf[t&1] => overwriting buf[t&1] at step t+1 is safe (lag-2).
//  hygiene: NOTHING is issued between the drain and the poll for wave 0
//           (vmcnt is in-order; any older op inflates every poll iter).
//           Waves 1-3 issue their noise/x prefetches DURING the poll window;
//           wave 0 prefetches and the out-store go after the A-loads.
__global__ void __launch_bounds__(256, 1)
rnn_persist(const float* __restrict__ x, const float* __restrict__ noise,
            const float* __restrict__ wi, const float* __restrict__ wrec,
            const float* __restrict__ wout, const float* __restrict__ bb,
            const float* __restrict__ gg, const float* __restrict__ h0,
            const float* __restrict__ mwrec, float* __restrict__ out)
{
    const int bid = blockIdx.x;
    const int grp = bid & 15;        // batch group (16 rows)
    const int ntw = bid >> 4;        // j-slice 0..15 (also producer id)
    const int jb  = ntw * 64;
    const int tid = threadIdx.x;
    const int w   = tid >> 6;        // wave = K-slice of 256
    const int l   = tid & 63;
    const int lm  = l & 15;
    const int lk  = l >> 4;
    const int kb  = w * 256;
    const int je  = jb + l;          // epilogue thread's j

    __shared__ float part[4 * 16 * 68];   // [wave][m][jj pad 68] fp32 partials
    __shared__ float xbuf[16 * 8];
    __shared__ float outred[64];

    // ---- per-thread constants ----
    float wiv[8];
#pragma unroll
    for (int i = 0; i < 8; ++i) wiv[i] = wi[i * H_ + je];
    const float bTe = bb[je];
    float h[4];
    {
        float h0j = h0[je];
        h[0] = h[1] = h[2] = h[3] = h0j;
    }

    // ---- B fragments: effWg[k][j] = relu(wrec[j,k]*ei[k])*ei[k]*mwrec[j,k]*relu(g[k]) ----
    // B layout (16x16x32): col = lane&15, k = kf*32 + 8*(lane>>4) + i
    short8 Bf[8][4];
#pragma unroll
    for (int kf = 0; kf < 8; ++kf) {
#pragma unroll
        for (int n4 = 0; n4 < 4; ++n4) {
            const int jB = jb + n4 * 16 + lm;
            const int k0 = kb + kf * 32 + 8 * lk;
            short8 r;
#pragma unroll
            for (int i = 0; i < 8; ++i) {
                const int k = k0 + i;
                const float ei = (k < EXC_N) ? 1.0f : -1.0f;
                const float wf = wrec[jB * H_ + k];
                const float mf = mwrec[jB * H_ + k];
                const float gf = fmaxf(gg[k], 0.0f);
                const float e  = fmaxf(wf * ei, 0.0f) * ei * mf * gf;
                r[i] = (short)f2bf(e);
            }
            Bf[kf][n4] = r;
        }
    }

    // ---- wout column slice (only WGs ntw<8 produce output column ntw) ----
    float wo[64];
    if (ntw < O_) {
#pragma unroll
        for (int kf = 0; kf < 8; ++kf)
#pragma unroll
            for (int i = 0; i < 8; ++i) {
                const int k = kb + kf * 32 + 8 * lk + i;
                wo[kf * 8 + i] = wout[k * O_ + ntw];
            }
    }

    // ---- A fragments for t=0: r0[k] = softplus(h0[k]+b[k]), same for all rows ----
    short8 Af[8];
#pragma unroll
    for (int kf = 0; kf < 8; ++kf) {
        const int k0 = kb + kf * 32 + 8 * lk;
        short8 a;
#pragma unroll
        for (int i = 0; i < 8; ++i)
            a[i] = (short)f2bf(sp_(h0[k0 + i] + bb[k0 + i]));
        Af[kf] = a;
    }

    // ---- prefetch noise(0), x(0) ----
    float nprev[4];
#pragma unroll
    for (int q = 0; q < 4; ++q)
        nprev[q] = noise[(grp * 16 + w * 4 + q) * (T_ * H_) + je];
    float xp = 0.0f;
    if (tid < 128) xp = x[(grp * 16 + (tid >> 3)) * (T_ * I_) + (tid & 7)];

    unsigned int* flg = g_flag + grp * 32;   // this group's 16-flag line

    for (int t = 0; t < NSTEP; ++t) {
        // stage x_t
        if (tid < 128) xbuf[tid] = xp;

        // MFMA: partial D = r_t @ effWg^T over this wave's K slice
        f32x4 acc0 = {0,0,0,0}, acc1 = {0,0,0,0}, acc2 = {0,0,0,0}, acc3 = {0,0,0,0};
#pragma unroll
        for (int kf = 0; kf < 8; ++kf) {
            acc0 = __builtin_amdgcn_mfma_f32_16x16x32_bf16(Af[kf], Bf[kf][0], acc0, 0, 0, 0);
            acc1 = __builtin_amdgcn_mfma_f32_16x16x32_bf16(Af[kf], Bf[kf][1], acc1, 0, 0, 0);
            acc2 = __builtin_amdgcn_mfma_f32_16x16x32_bf16(Af[kf], Bf[kf][2], acc2, 0, 0, 0);
            acc3 = __builtin_amdgcn_mfma_f32_16x16x32_bf16(Af[kf], Bf[kf][3], acc3, 0, 0, 0);
        }
        // D layout: m = 4*lk + reg, jj = n4*16 + lm
#pragma unroll
        for (int reg = 0; reg < 4; ++reg) {
            const int m = 4 * lk + reg;
            part[(w * 16 + m) * 68 +  0 + lm] = acc0[reg];
            part[(w * 16 + m) * 68 + 16 + lm] = acc1[reg];
            part[(w * 16 + m) * 68 + 32 + lm] = acc2[reg];
            part[(w * 16 + m) * 68 + 48 + lm] = acc3[reg];
        }
        __syncthreads();   // (a)

        // h update (fp32 state in regs), produce r_{t+1} (bf16)
        u16 rsto[4];
#pragma unroll
        for (int q = 0; q < 4; ++q) {
            const int m = w * 4 + q;
            float D = part[(0 * 16 + m) * 68 + l] + part[(1 * 16 + m) * 68 + l]
                    + part[(2 * 16 + m) * 68 + l] + part[(3 * 16 + m) * 68 + l];
            float inp = 0.0f;
#pragma unroll
            for (int i = 0; i < 8; ++i) inp = fmaf(xbuf[m * 8 + i], wiv[i], inp);
            float hn = h[q] + 0.05f * nprev[q] + 0.2f * (-h[q] + D + inp);
            hn = fminf(fmaxf(hn, -64.0f), 64.0f);   // inert if dynamics correct (|h|<~20)
            h[q] = hn;
            rsto[q] = f2bf(sp_(hn + bTe));
        }

        // r store: pair-pack adjacent lanes' bf16 into u32, coherent store
        // (write guard is implied by last step's all-16 poll — see header)
        {
            unsigned int* rb32 = (unsigned int*)(g_rbuf + ((t + 1) & 1) * (B_ * H_)
                                                 + (grp * 16) * H_);
#pragma unroll
            for (int q = 0; q < 4; ++q) {
                unsigned int mine = (unsigned int)rsto[q];
                unsigned int nb   = (unsigned int)__shfl_xor((int)mine, 1, 64);
                if ((l & 1) == 0) {
                    unsigned int packed = (mine & 0xffffu) | (nb << 16);
                    __hip_atomic_store(rb32 + (((w * 4 + q) * H_ + je) >> 1), packed,
                                       __ATOMIC_RELAXED, __HIP_MEMORY_SCOPE_AGENT);
                }
            }
        }

        // output row t from r_t (Af): VALU compute BEFORE the drain so the
        // r-store acks arrive underneath it; the global store is deferred to
        // after the A-loads.
        float outval = 0.0f;
        if (ntw < O_) {
            float po = 0.0f;
#pragma unroll
            for (int kf = 0; kf < 8; ++kf) {
                const short8 a = Af[kf];
#pragma unroll
                for (int i = 0; i < 8; ++i)
                    po = fmaf(bf2f((u16)a[i]), wo[kf * 8 + i], po);
            }
            po += __shfl_xor(po, 16, 64);
            po += __shfl_xor(po, 32, 64);
            if (l < 16) outred[w * 16 + l] = po;
            __syncthreads();   // (c)
            if (tid < 16)
                outval = outred[tid] + outred[16 + tid] + outred[32 + tid] + outred[48 + tid];
        }

        // release edge: drain this wave's coherent stores, barrier across the
        // 4 waves, then ONE-WAY flag store (no RMW, no cache maintenance).
        asm volatile("s_waitcnt vmcnt(0)" ::: "memory");
        __syncthreads();   // (b)
        if (tid == 0)
            __hip_atomic_store(flg + ntw, (unsigned int)(t + 1),
                               __ATOMIC_RELAXED, __HIP_MEMORY_SCOPE_AGENT);
        asm volatile("" ::: "memory");   // keep the flag store above the poll

        // waves 1-3: issue next-step stream prefetches now — their HBM latency
        // hides under the poll window while they wait at barrier (d).
        if (w != 0) {
#pragma unroll
            for (int q = 0; q < 4; ++q)
                nprev[q] = noise[(grp * 16 + w * 4 + q) * (T_ * H_) + (t + 1) * H_ + je];
            if (tid < 128)   // wave 1 holds x rows 8..15
                xp = x[(grp * 16 + (tid >> 3)) * (T_ * I_) + (t + 1) * I_ + (tid & 7)];
        }

        // acquire edge: wave 0 polls the 16-flag line with a clean vmcnt
        // shadow (nothing outstanding) — one coalesced 64B request per iter.
        if (w == 0) {
            const unsigned int tgt = (unsigned int)(t + 1);
            unsigned int f;
            do {
                f = __hip_atomic_load(flg + lm, __ATOMIC_RELAXED,
                                      __HIP_MEMORY_SCOPE_AGENT);
            } while (__any((int)(f < tgt)));
        }
        __syncthreads();   // (d)

        // A-frag loads for r_{t+1} (coherent u64 atomic loads) — issued first
        // so nothing younger sits in front of them in the vmcnt queue.
        {
            u16* rbl = g_rbuf + ((t + 1) & 1) * (B_ * H_) + (grp * 16 + lm) * H_ + kb;
#pragma unroll
            for (int kf = 0; kf < 8; ++kf) {
                unsigned long long* p = (unsigned long long*)(rbl + kf * 32 + 8 * lk);
                unsigned long long d0 = __hip_atomic_load(p + 0, __ATOMIC_RELAXED,
                                                          __HIP_MEMORY_SCOPE_AGENT);
                unsigned long long d1 = __hip_atomic_load(p + 1, __ATOMIC_RELAXED,
                                                          __HIP_MEMORY_SCOPE_AGENT);
                union { unsigned long long q[2]; short8 s; } cv;
                cv.q[0] = d0; cv.q[1] = d1;
                Af[kf] = cv.s;
            }
        }

        // wave 0's prefetches + deferred out store (fire & forget; overlap
        // with next iteration's MFMA)
        if (w == 0) {
#pragma unroll
            for (int q = 0; q < 4; ++q)
                nprev[q] = noise[(grp * 16 + q) * (T_ * H_) + (t + 1) * H_ + je];
            xp = x[(grp * 16 + (tid >> 3)) * (T_ * I_) + (t + 1) * I_ + (tid & 7)];
        }
        if (ntw < O_ && tid < 16)
            out[(grp * 16 + tid) * (T_ * O_) + t * O_ + ntw] = outval;
    }

    // output row T-1 from r_{T-1}
    if (ntw < O_) {
        float po = 0.0f;
#pragma unroll
        for (int kf = 0; kf < 8; ++kf) {
            const short8 a = Af[kf];
#pragma unroll
            for (int i = 0; i < 8; ++i)
                po = fmaf(bf2f((u16)a[i]), wo[kf * 8 + i], po);
        }
        po += __shfl_xor(po, 16, 64);
        po += __shfl_xor(po, 32, 64);
        if (l < 16) outred[w * 16 + l] = po;
        __syncthreads();
        if (tid < 16) {
            float s = outred[tid] + outred[16 + tid] + outred[32 + tid] + outred[48 + tid];
            out[(grp * 16 + tid) * (T_ * O_) + (T_ - 1) * O_ + ntw] = s;
        }
    }
}

extern "C" void kernel_launch(void* const* d_in, const int* in_sizes, int n_in,
                              void* d_out, int out_size, void* d_ws, size_t ws_size,
                              hipStream_t stream) {
    (void)in_sizes; (void)n_in; (void)out_size; (void)d_ws; (void)ws_size;
    const float* x     = (const float*)d_in[0];
    const float* noise = (const float*)d_in[1];
    const float* wi    = (const float*)d_in[2];
    const float* wrec  = (const float*)d_in[3];
    const float* wout  = (const float*)d_in[4];
    const float* bb    = (const float*)d_in[5];
    const float* gg    = (const float*)d_in[6];
    const float* h0    = (const float*)d_in[7];
    // d_in[8] = refEI: derived analytically (ei[k] = k<819 ? 1 : -1), not needed
    const float* mwrec = (const float*)d_in[9];
    float* out = (float*)d_out;

    rnn_init<<<dim3(1), dim3(256), 0, stream>>>();
    rnn_persist<<<dim3(256), dim3(256), 0, stream>>>(
        x, noise, wi, wrec, wout, bb, gg, h0, mwrec, out);
}

// Round 4
// 2767.021 us; speedup vs baseline: 1.2165x; 1.1145x over previous
//
#include <hip/hip_runtime.h>

#define B_ 256
#define T_ 500
#define I_ 8
#define H_ 1024
#define O_ 8
#define NSTEP (T_ - 1)
#define EXC_N 819   // int(0.8 * 1024)

typedef unsigned short u16;
typedef __attribute__((ext_vector_type(8))) short short8;
typedef __attribute__((ext_vector_type(4))) float f32x4;
typedef __attribute__((ext_vector_type(4))) unsigned int u32x4;

// r-exchange ping-pong in module globals (d_ws size unknown; .bss is safe).
__device__ __attribute__((aligned(16))) u16 g_rbuf[2 * B_ * H_];

__device__ __forceinline__ float bf2f(u16 u) {
    union { unsigned int i; float f; } v;
    v.i = ((unsigned int)u) << 16;
    return v.f;
}
__device__ __forceinline__ u16 f2bf(float f) {
    union { float f; unsigned int i; } v;
    v.f = f;
    unsigned int u = v.i;
    return (u16)((u + 0x7fffu + ((u >> 16) & 1u)) >> 16);
}
__device__ __forceinline__ float sp_(float v) {   // softplus, beta=1
    float e = __expf(-fabsf(v));
    return fmaxf(v, 0.0f) + __logf(1.0f + e);
}

// Re-stamp both r buffers every launch: sign-bit phase tags must be INVALID
// for the first expected phases (r_1 in buf1 expects S=0 -> init buf1 sign=1;
// r_2 in buf0 expects S=1 -> init buf0 sign=0). Also erases stale data from a
// previous graph replay. Kernel-boundary release makes this visible to the
// coherent loads of rnn_persist.
__global__ void rnn_init() {
    const unsigned int idx = blockIdx.x * 256 + threadIdx.x;   // 0..65535
    u32x4* p = (u32x4*)g_rbuf;                                  // 65536 x 16B
    const unsigned int z = 0u, s = 0x80008000u;
    p[idx] = (idx < 32768u) ? (u32x4){z, z, z, z} : (u32x4){s, s, s, s};
}

// SYNC SCHEME (R4 — data-embedded phase stamps, zero-fence zero-flag):
//  r = softplus(.) >= 0, so bf16 sign bit is free. r_t is stored into
//  buf[t&1] with every value's sign bit = S(t) = (t>>1)&1 (alternates on
//  each reuse of a buffer). Consumers poll their OWN A-frag loads (coherent
//  u64 loads) until all sign bits match S, then mask the bits off. The
//  successful poll IS the data load: store -> one-way flight -> poll catch.
//  No vmcnt drain, no flag, no release/acquire barriers.
//  Write guard (lag-2, free): a wave reaches step t's r-store only after
//  sync(a)@t, which gathers all 4 waves, whose polls for r_t collectively
//  certify all 16 producer WGs stored r_t => every wave of every WG in the
//  group consumed r_{t-1} => overwriting buf[(t+1)&1] is safe.
//  part/xbuf are DOUBLE-BUFFERED (pp=t&1): without barriers (b)/(d), a fast
//  wave's step-t+1 LDS writes could race a slow sibling's step-t reads.
__global__ void __launch_bounds__(256, 1)
rnn_persist(const float* __restrict__ x, const float* __restrict__ noise,
            const float* __restrict__ wi, const float* __restrict__ wrec,
            const float* __restrict__ wout, const float* __restrict__ bb,
            const float* __restrict__ gg, const float* __restrict__ h0,
            const float* __restrict__ mwrec, float* __restrict__ out)
{
    const int bid = blockIdx.x;
    const int grp = bid & 15;        // batch group (16 rows)
    const int ntw = bid >> 4;        // j-slice 0..15
    const int jb  = ntw * 64;
    const int tid = threadIdx.x;
    const int w   = tid >> 6;        // wave = K-slice of 256
    const int l   = tid & 63;
    const int lm  = l & 15;
    const int lk  = l >> 4;
    const int kb  = w * 256;
    const int je  = jb + l;          // epilogue thread's j

    __shared__ float part[2][4 * 16 * 68];   // [pp][wave][m][jj pad 68]
    __shared__ float xbuf[2][16 * 8];
    __shared__ float outred[64];

    // ---- per-thread constants ----
    float wiv[8];
#pragma unroll
    for (int i = 0; i < 8; ++i) wiv[i] = wi[i * H_ + je];
    const float bTe = bb[je];
    float h[4];
    {
        float h0j = h0[je];
        h[0] = h[1] = h[2] = h[3] = h0j;
    }

    // ---- B fragments: effWg[k][j] = relu(wrec[j,k]*ei[k])*ei[k]*mwrec[j,k]*relu(g[k]) ----
    // B layout (16x16x32): col = lane&15, k = kf*32 + 8*(lane>>4) + i
    short8 Bf[8][4];
#pragma unroll
    for (int kf = 0; kf < 8; ++kf) {
#pragma unroll
        for (int n4 = 0; n4 < 4; ++n4) {
            const int jB = jb + n4 * 16 + lm;
            const int k0 = kb + kf * 32 + 8 * lk;
            short8 r;
#pragma unroll
            for (int i = 0; i < 8; ++i) {
                const int k = k0 + i;
                const float ei = (k < EXC_N) ? 1.0f : -1.0f;
                const float wf = wrec[jB * H_ + k];
                const float mf = mwrec[jB * H_ + k];
                const float gf = fmaxf(gg[k], 0.0f);
                const float e  = fmaxf(wf * ei, 0.0f) * ei * mf * gf;
                r[i] = (short)f2bf(e);
            }
            Bf[kf][n4] = r;
        }
    }

    // ---- wout column slice (only WGs ntw<8 produce output column ntw) ----
    float wo[64];
    if (ntw < O_) {
#pragma unroll
        for (int kf = 0; kf < 8; ++kf)
#pragma unroll
            for (int i = 0; i < 8; ++i) {
                const int k = kb + kf * 32 + 8 * lk + i;
                wo[kf * 8 + i] = wout[k * O_ + ntw];
            }
    }

    // ---- A fragments for t=0: r0[k] = softplus(h0[k]+b[k]) (no stamps) ----
    short8 Af[8];
#pragma unroll
    for (int kf = 0; kf < 8; ++kf) {
        const int k0 = kb + kf * 32 + 8 * lk;
        short8 a;
#pragma unroll
        for (int i = 0; i < 8; ++i)
            a[i] = (short)f2bf(sp_(h0[k0 + i] + bb[k0 + i]));
        Af[kf] = a;
    }

    // ---- prefetch noise(0), x(0) ----
    float nprev[4];
#pragma unroll
    for (int q = 0; q < 4; ++q)
        nprev[q] = noise[(grp * 16 + w * 4 + q) * (T_ * H_) + je];
    float xp = 0.0f;
    if (tid < 128) xp = x[(grp * 16 + (tid >> 3)) * (T_ * I_) + (tid & 7)];

    for (int t = 0; t < NSTEP; ++t) {
        const int pp = t & 1;
        // stage x_t
        if (tid < 128) xbuf[pp][tid] = xp;

        // MFMA: partial D = r_t @ effWg^T over this wave's K slice
        f32x4 acc0 = {0,0,0,0}, acc1 = {0,0,0,0}, acc2 = {0,0,0,0}, acc3 = {0,0,0,0};
#pragma unroll
        for (int kf = 0; kf < 8; ++kf) {
            acc0 = __builtin_amdgcn_mfma_f32_16x16x32_bf16(Af[kf], Bf[kf][0], acc0, 0, 0, 0);
            acc1 = __builtin_amdgcn_mfma_f32_16x16x32_bf16(Af[kf], Bf[kf][1], acc1, 0, 0, 0);
            acc2 = __builtin_amdgcn_mfma_f32_16x16x32_bf16(Af[kf], Bf[kf][2], acc2, 0, 0, 0);
            acc3 = __builtin_amdgcn_mfma_f32_16x16x32_bf16(Af[kf], Bf[kf][3], acc3, 0, 0, 0);
        }
        // D layout: m = 4*lk + reg, jj = n4*16 + lm
#pragma unroll
        for (int reg = 0; reg < 4; ++reg) {
            const int m = 4 * lk + reg;
            part[pp][(w * 16 + m) * 68 +  0 + lm] = acc0[reg];
            part[pp][(w * 16 + m) * 68 + 16 + lm] = acc1[reg];
            part[pp][(w * 16 + m) * 68 + 32 + lm] = acc2[reg];
            part[pp][(w * 16 + m) * 68 + 48 + lm] = acc3[reg];
        }
        __syncthreads();   // (a) — also the write-guard gather (see header)

        // h update (fp32 state in regs), produce r_{t+1} (bf16, phase-stamped)
        const u16 sbit = (u16)(((((unsigned)(t + 1)) >> 1) & 1u) << 15);
        u16 rsto[4];
#pragma unroll
        for (int q = 0; q < 4; ++q) {
            const int m = w * 4 + q;
            float D = part[pp][(0 * 16 + m) * 68 + l] + part[pp][(1 * 16 + m) * 68 + l]
                    + part[pp][(2 * 16 + m) * 68 + l] + part[pp][(3 * 16 + m) * 68 + l];
            float inp = 0.0f;
#pragma unroll
            for (int i = 0; i < 8; ++i) inp = fmaf(xbuf[pp][m * 8 + i], wiv[i], inp);
            float hn = h[q] + 0.05f * nprev[q] + 0.2f * (-h[q] + D + inp);
            hn = fminf(fmaxf(hn, -64.0f), 64.0f);   // inert if dynamics correct (|h|<~20)
            h[q] = hn;
            rsto[q] = (u16)(f2bf(sp_(hn + bTe)) | sbit);
        }
        // r store: pair-pack adjacent lanes' bf16 into u32, coherent store,
        // fire & forget (no drain — consumers validate via the stamp)
        {
            unsigned int* rb32 = (unsigned int*)(g_rbuf + ((t + 1) & 1) * (B_ * H_)
                                                 + (grp * 16) * H_);
#pragma unroll
            for (int q = 0; q < 4; ++q) {
                unsigned int mine = (unsigned int)rsto[q];
                unsigned int nb   = (unsigned int)__shfl_xor((int)mine, 1, 64);
                if ((l & 1) == 0) {
                    unsigned int packed = (mine & 0xffffu) | (nb << 16);
                    __hip_atomic_store(rb32 + (((w * 4 + q) * H_ + je) >> 1), packed,
                                       __ATOMIC_RELAXED, __HIP_MEMORY_SCOPE_AGENT);
                }
            }
        }

        // next-step stream prefetch NOW (its latency hides under the poll;
        // it inflates only the first poll iteration's waitcnt)
#pragma unroll
        for (int q = 0; q < 4; ++q)
            nprev[q] = noise[(grp * 16 + w * 4 + q) * (T_ * H_) + (t + 1) * H_ + je];
        if (tid < 128 && t + 1 < NSTEP)
            xp = x[(grp * 16 + (tid >> 3)) * (T_ * I_) + (t + 1) * I_ + (tid & 7)];

        // output row t from r_t (Af, already unstamped): compute + LDS reduce
        // BEFORE the poll (fills the wait window); global store deferred.
        float outval = 0.0f;
        if (ntw < O_) {
            float po = 0.0f;
#pragma unroll
            for (int kf = 0; kf < 8; ++kf) {
                const short8 a = Af[kf];
#pragma unroll
                for (int i = 0; i < 8; ++i)
                    po = fmaf(bf2f((u16)a[i]), wo[kf * 8 + i], po);
            }
            po += __shfl_xor(po, 16, 64);
            po += __shfl_xor(po, 32, 64);
            if (l < 16) outred[w * 16 + l] = po;
            __syncthreads();   // (c)
            if (tid < 16)
                outval = outred[tid] + outred[16 + tid] + outred[32 + tid] + outred[48 + tid];
        }

        // acquire = the A-frag loads themselves: poll until every value's
        // sign bit matches S(t+1), then mask stamps off. Per-lane divergent
        // loop: passed lanes stop re-issuing loads (exec-masked).
        {
            const unsigned long long SM = 0x8000800080008000ull;
            const unsigned long long SE = (((unsigned)(t + 1) >> 1) & 1u) ? SM : 0ull;
            u16* rbl = g_rbuf + ((t + 1) & 1) * (B_ * H_) + (grp * 16 + lm) * H_ + kb;
            unsigned long long d0[8], d1[8];
            int ok;
            do {
#pragma unroll
                for (int kf = 0; kf < 8; ++kf) {
                    unsigned long long* p = (unsigned long long*)(rbl + kf * 32 + 8 * lk);
                    d0[kf] = __hip_atomic_load(p + 0, __ATOMIC_RELAXED,
                                               __HIP_MEMORY_SCOPE_AGENT);
                    d1[kf] = __hip_atomic_load(p + 1, __ATOMIC_RELAXED,
                                               __HIP_MEMORY_SCOPE_AGENT);
                }
                unsigned long long bad = 0ull;
#pragma unroll
                for (int kf = 0; kf < 8; ++kf)
                    bad |= ((d0[kf] ^ SE) & SM) | ((d1[kf] ^ SE) & SM);
                ok = (bad == 0ull);
            } while (!ok);
#pragma unroll
            for (int kf = 0; kf < 8; ++kf) {
                union { unsigned long long q[2]; short8 s; } cv;
                cv.q[0] = d0[kf] & ~SM;
                cv.q[1] = d1[kf] & ~SM;
                Af[kf] = cv.s;
            }
        }

        // deferred out store (fire & forget; overlaps next step's MFMA)
        if (ntw < O_ && tid < 16)
            out[(grp * 16 + tid) * (T_ * O_) + t * O_ + ntw] = outval;
    }

    // output row T-1 from r_{T-1}
    __syncthreads();   // guard outred reuse vs last in-loop read
    if (ntw < O_) {
        float po = 0.0f;
#pragma unroll
        for (int kf = 0; kf < 8; ++kf) {
            const short8 a = Af[kf];
#pragma unroll
            for (int i = 0; i < 8; ++i)
                po = fmaf(bf2f((u16)a[i]), wo[kf * 8 + i], po);
        }
        po += __shfl_xor(po, 16, 64);
        po += __shfl_xor(po, 32, 64);
        if (l < 16) outred[w * 16 + l] = po;
        __syncthreads();
        if (tid < 16) {
            float s = outred[tid] + outred[16 + tid] + outred[32 + tid] + outred[48 + tid];
            out[(grp * 16 + tid) * (T_ * O_) + (T_ - 1) * O_ + ntw] = s;
        }
    }
}

extern "C" void kernel_launch(void* const* d_in, const int* in_sizes, int n_in,
                              void* d_out, int out_size, void* d_ws, size_t ws_size,
                              hipStream_t stream) {
    (void)in_sizes; (void)n_in; (void)out_size; (void)d_ws; (void)ws_size;
    const float* x     = (const float*)d_in[0];
    const float* noise = (const float*)d_in[1];
    const float* wi    = (const float*)d_in[2];
    const float* wrec  = (const float*)d_in[3];
    const float* wout  = (const float*)d_in[4];
    const float* bb    = (const float*)d_in[5];
    const float* gg    = (const float*)d_in[6];
    const float* h0    = (const float*)d_in[7];
    // d_in[8] = refEI: derived analytically (ei[k] = k<819 ? 1 : -1), not needed
    const float* mwrec = (const float*)d_in[9];
    float* out = (float*)d_out;

    rnn_init<<<dim3(256), dim3(256), 0, stream>>>();
    rnn_persist<<<dim3(256), dim3(256), 0, stream>>>(
        x, noise, wi, wrec, wout, bb, gg, h0, mwrec, out);
}